// Round 1
// baseline (11576.294 us; speedup 1.0000x reference)
//
#include <hip/hip_runtime.h>
#include <math.h>

#define SS 2048
#define EE 1024
#define EPSD 1e-8
#define NTH 1024

__device__ __forceinline__ double wave_sum64(double v) {
#pragma unroll
  for (int off = 32; off > 0; off >>= 1) v += __shfl_down(v, off, 64);
  return v;
}

// Kernel A: gather x0 = emb[seqs] (store as T), compute row norms in double.
template <typename T>
__global__ void banyan_init(const int* __restrict__ seqs, const float* __restrict__ emb,
                            T* __restrict__ x, double* __restrict__ norms) {
  __shared__ double sh[4];
  const int s = blockIdx.x;
  const int row = seqs[s];
  double acc = 0.0;
  for (int e = threadIdx.x; e < EE; e += 256) {
    const float v = emb[(size_t)row * EE + e];
    x[(size_t)s * EE + e] = (T)v;
    acc += (double)v * (double)v;
  }
  acc = wave_sum64(acc);
  const int lane = threadIdx.x & 63;
  const int w = threadIdx.x >> 6;
  if (lane == 0) sh[w] = acc;
  __syncthreads();
  if (threadIdx.x == 0) norms[s] = sqrt(sh[0] + sh[1] + sh[2] + sh[3]);
}

// Kernel B: initial adjacent-pair dot products in double.
template <typename T>
__global__ void banyan_dots(const T* __restrict__ x, double* __restrict__ num) {
  __shared__ double sh[4];
  const int s = blockIdx.x;  // 0..SS-2
  double acc = 0.0;
  for (int e = threadIdx.x; e < EE; e += 256) {
    acc += (double)x[(size_t)s * EE + e] * (double)x[(size_t)(s + 1) * EE + e];
  }
  acc = wave_sum64(acc);
  const int lane = threadIdx.x & 63;
  const int w = threadIdx.x >> 6;
  if (lane == 0) sh[w] = acc;
  __syncthreads();
  if (threadIdx.x == 0) num[s] = sh[0] + sh[1] + sh[2] + sh[3];
}

// Kernel C: persistent single-block greedy merge loop.
// Linked list + cached cosines in LDS; per step only the merged node's
// neighborhood changes (2 cosines + 1 norm), matching the reference's full
// recomputation exactly (same values, f64 precision).
template <typename T>
__global__ __launch_bounds__(NTH) void banyan_main(
    T* __restrict__ x, const double* __restrict__ norms_in, const double* __restrict__ num_in,
    const float* __restrict__ Wl, const float* __restrict__ Wr, const float* __restrict__ Bb,
    float* __restrict__ out) {
  __shared__ double cosL[SS];
  __shared__ double normL[SS];
  __shared__ int nextL[SS];
  __shared__ int prevL[SS];
  __shared__ double wmax[16];
  __shared__ int widx[16];
  __shared__ double r3[16][3];
  __shared__ int sel[2];

  const int t = threadIdx.x;
  const int lane = t & 63;
  const int w = t >> 6;
  const double NEGINF = -__builtin_inf();

  for (int s = t; s < SS; s += NTH) {
    normL[s] = norms_in[s];
    nextL[s] = (s + 1 < SS) ? (s + 1) : -1;
    prevL[s] = s - 1;
  }
  __syncthreads();
  for (int s = t; s < SS; s += NTH) {
    cosL[s] = (s < SS - 1)
                  ? num_in[s] / (fmax(normL[s], EPSD) * fmax(normL[s + 1], EPSD))
                  : NEGINF;
  }
  __syncthreads();

  // Thread t owns element t of every row (EE == NTH).
  const double wl = (double)Wl[t];
  const double wr = (double)Wr[t];
  const double bv = (double)Bb[t];
  int head = 0;  // uniform across threads (updated from uniform values)

  for (int step = 0; step < SS - 1; ++step) {
    // ---- argmax over cosL with first-occurrence (smallest index) tie-break ----
    double bc = cosL[t];
    int bi = t;
    {
      const double c2 = cosL[t + NTH];
      if (c2 > bc) { bc = c2; bi = t + NTH; }  // strict > keeps smaller index on tie
    }
#pragma unroll
    for (int off = 32; off > 0; off >>= 1) {
      const double oc = __shfl_down(bc, off, 64);
      const int oi = __shfl_down(bi, off, 64);
      if (oc > bc || (oc == bc && oi < bi)) { bc = oc; bi = oi; }
    }
    if (lane == 0) { wmax[w] = bc; widx[w] = bi; }
    __syncthreads();
    if (t == 0) {
      double fb = wmax[0];
      int fi = widx[0];
#pragma unroll
      for (int k = 1; k < 16; ++k) {
        if (wmax[k] > fb || (wmax[k] == fb && widx[k] < fi)) { fb = wmax[k]; fi = widx[k]; }
      }
      sel[0] = fi;
      sel[1] = nextL[fi];
    }
    __syncthreads();
    const int i = sel[0];
    const int j = sel[1];
    const int p = prevL[i];   // stable: list only mutated by t0 after next barrier
    const int nj = nextL[j];
    if (p < 0) head = j;      // i was the head; j replaces it

    // ---- parent = tanh(xi*Wl + xj*Wr + b); fused 3-way reduction ----
    const double xi = (double)x[(size_t)i * EE + t];
    const double xj = (double)x[(size_t)j * EE + t];
    const double par = tanh(xi * wl + xj * wr + bv);
    x[(size_t)j * EE + t] = (T)par;
    double s0 = par * par;                                            // ||parent||^2
    double s1 = (p >= 0) ? (double)x[(size_t)p * EE + t] * par : 0.0; // dot(x[p], parent)
    double s2 = (nj >= 0) ? par * (double)x[(size_t)nj * EE + t] : 0.0; // dot(parent, x[nj])
#pragma unroll
    for (int off = 32; off > 0; off >>= 1) {
      s0 += __shfl_down(s0, off, 64);
      s1 += __shfl_down(s1, off, 64);
      s2 += __shfl_down(s2, off, 64);
    }
    if (lane == 0) { r3[w][0] = s0; r3[w][1] = s1; r3[w][2] = s2; }
    __syncthreads();
    if (t == 0) {
      double t0 = 0.0, t1 = 0.0, t2 = 0.0;
#pragma unroll
      for (int k = 0; k < 16; ++k) { t0 += r3[k][0]; t1 += r3[k][1]; t2 += r3[k][2]; }
      const double nn = sqrt(t0);
      normL[j] = nn;
      cosL[i] = NEGINF;
      prevL[j] = p;
      if (p >= 0) {
        nextL[p] = j;
        cosL[p] = t1 / (fmax(normL[p], EPSD) * fmax(nn, EPSD));
      }
      cosL[j] = (nj >= 0) ? t2 / (fmax(nn, EPSD) * fmax(normL[nj], EPSD)) : NEGINF;
    }
    __syncthreads();
  }

  // Exactly one valid slot remains: the list head.
  out[t] = (float)x[(size_t)head * EE + t];
}

extern "C" void kernel_launch(void* const* d_in, const int* in_sizes, int n_in,
                              void* d_out, int out_size, void* d_ws, size_t ws_size,
                              hipStream_t stream) {
  const int* seqs = (const int*)d_in[0];
  const float* emb = (const float*)d_in[1];
  const float* Wl = (const float*)d_in[2];
  const float* Wr = (const float*)d_in[3];
  const float* Bb = (const float*)d_in[4];
  float* out = (float*)d_out;

  const size_t auxBytes = 2 * (size_t)SS * sizeof(double);
  const size_t xbytesD = (size_t)SS * EE * sizeof(double);

  if (ws_size >= xbytesD + auxBytes) {
    // Preferred: float64 storage for maximal fidelity to the numpy reference.
    double* x = (double*)d_ws;
    double* norms = (double*)((char*)d_ws + xbytesD);
    double* num = norms + SS;
    hipLaunchKernelGGL((banyan_init<double>), dim3(SS), dim3(256), 0, stream, seqs, emb, x, norms);
    hipLaunchKernelGGL((banyan_dots<double>), dim3(SS - 1), dim3(256), 0, stream, x, num);
    hipLaunchKernelGGL((banyan_main<double>), dim3(1), dim3(NTH), 0, stream,
                       x, norms, num, Wl, Wr, Bb, out);
  } else {
    // Fallback: float32 storage, float64 arithmetic.
    const size_t xbytesF = (size_t)SS * EE * sizeof(float);
    float* x = (float*)d_ws;
    double* norms = (double*)((char*)d_ws + xbytesF);
    double* num = norms + SS;
    hipLaunchKernelGGL((banyan_init<float>), dim3(SS), dim3(256), 0, stream, seqs, emb, x, norms);
    hipLaunchKernelGGL((banyan_dots<float>), dim3(SS - 1), dim3(256), 0, stream, x, num);
    hipLaunchKernelGGL((banyan_main<float>), dim3(1), dim3(NTH), 0, stream,
                       x, norms, num, Wl, Wr, Bb, out);
  }
}

// Round 2
// 6691.573 us; speedup vs baseline: 1.7300x; 1.7300x over previous
//
#include <hip/hip_runtime.h>
#include <math.h>

#define SS 2048
#define EE 1024
#define EPSD 1e-8
#define NTH 256          // 4 waves
#define EPT 4            // elements per thread (EE / NTH)
#define SPT 8            // cosine slots per thread (SS / NTH)
#define NW  4            // waves

__device__ __forceinline__ double wave_sum64(double v) {
#pragma unroll
  for (int off = 32; off > 0; off >>= 1) v += __shfl_down(v, off, 64);
  return v;
}

// Kernel A: gather x0 = emb[seqs] (store as T), compute row norms in double.
template <typename T>
__global__ void banyan_init(const int* __restrict__ seqs, const float* __restrict__ emb,
                            T* __restrict__ x, double* __restrict__ norms) {
  __shared__ double sh[4];
  const int s = blockIdx.x;
  const int row = seqs[s];
  double acc = 0.0;
  for (int e = threadIdx.x; e < EE; e += 256) {
    const float v = emb[(size_t)row * EE + e];
    x[(size_t)s * EE + e] = (T)v;
    acc += (double)v * (double)v;
  }
  acc = wave_sum64(acc);
  const int lane = threadIdx.x & 63;
  const int w = threadIdx.x >> 6;
  if (lane == 0) sh[w] = acc;
  __syncthreads();
  if (threadIdx.x == 0) norms[s] = sqrt(sh[0] + sh[1] + sh[2] + sh[3]);
}

// Kernel B: initial adjacent-pair dot products in double.
template <typename T>
__global__ void banyan_dots(const T* __restrict__ x, double* __restrict__ num) {
  __shared__ double sh[4];
  const int s = blockIdx.x;  // 0..SS-2
  double acc = 0.0;
  for (int e = threadIdx.x; e < EE; e += 256) {
    acc += (double)x[(size_t)s * EE + e] * (double)x[(size_t)(s + 1) * EE + e];
  }
  acc = wave_sum64(acc);
  const int lane = threadIdx.x & 63;
  const int w = threadIdx.x >> 6;
  if (lane == 0) sh[w] = acc;
  __syncthreads();
  if (threadIdx.x == 0) num[s] = sh[0] + sh[1] + sh[2] + sh[3];
}

// Kernel C: persistent single-block greedy merge loop, 4 waves.
// Linked list + cached cosines in LDS. Per step: 3 barriers, redundant
// uniform combine (no t0-serial argmax section, no selection broadcast).
template <typename T>
__global__ __launch_bounds__(NTH) void banyan_main(
    T* __restrict__ x, const double* __restrict__ norms_in, const double* __restrict__ num_in,
    const float* __restrict__ Wl, const float* __restrict__ Wr, const float* __restrict__ Bb,
    float* __restrict__ out) {
  __shared__ double cosL[SS];
  __shared__ double normL[SS];
  __shared__ int nextL[SS];
  __shared__ int prevL[SS];
  __shared__ double wmax[NW];
  __shared__ int widx[NW];
  __shared__ double r3[NW][3];

  const int t = threadIdx.x;
  const int lane = t & 63;
  const int w = t >> 6;
  const double NEGINF = -__builtin_inf();

  for (int s = t; s < SS; s += NTH) {
    normL[s] = norms_in[s];
    nextL[s] = (s + 1 < SS) ? (s + 1) : -1;
    prevL[s] = s - 1;
  }
  __syncthreads();
  for (int s = t; s < SS; s += NTH) {
    cosL[s] = (s < SS - 1)
                  ? num_in[s] / (fmax(normL[s], EPSD) * fmax(normL[s + 1], EPSD))
                  : NEGINF;
  }
  __syncthreads();

  // Thread t owns elements e = t + 256*k, k = 0..3 (coalesced per wave).
  double wl[EPT], wr[EPT], bv[EPT];
#pragma unroll
  for (int k = 0; k < EPT; ++k) {
    const int e = t + k * NTH;
    wl[k] = (double)Wl[e];
    wr[k] = (double)Wr[e];
    bv[k] = (double)Bb[e];
  }
  int head = 0;  // uniform across threads

  for (int step = 0; step < SS - 1; ++step) {
    // ---- argmax over cosL, first-occurrence (smallest index) tie-break ----
    double bc = cosL[t];
    int bi = t;
#pragma unroll
    for (int k = 1; k < SPT; ++k) {
      const int s = t + k * NTH;          // ascending index within thread
      const double c = cosL[s];
      if (c > bc) { bc = c; bi = s; }     // strict > keeps smaller index on tie
    }
#pragma unroll
    for (int off = 32; off > 0; off >>= 1) {
      const double oc = __shfl_down(bc, off, 64);
      const int oi = __shfl_down(bi, off, 64);
      if (oc > bc || (oc == bc && oi < bi)) { bc = oc; bi = oi; }
    }
    if (lane == 0) { wmax[w] = bc; widx[w] = bi; }
    __syncthreads();   // barrier A

    // Redundant uniform combine: all threads compute identical (i, j).
    double fb = wmax[0];
    int fi = widx[0];
#pragma unroll
    for (int k = 1; k < NW; ++k) {
      const double c = wmax[k];
      const int ii = widx[k];
      if (c > fb || (c == fb && ii < fi)) { fb = c; fi = ii; }
    }
    const int i = fi;
    const int j = nextL[fi];   // broadcast LDS read (same addr, free)
    const int p = prevL[i];
    const int nj = nextL[j];
    if (p < 0) head = j;       // uniform update

    // ---- load all four rows in one latency window (clamped indices) ----
    const int p2 = (p >= 0) ? p : i;
    const int n2 = (nj >= 0) ? nj : i;
    double xi[EPT], xj[EPT], xp[EPT], xn[EPT];
#pragma unroll
    for (int k = 0; k < EPT; ++k) {
      const int e = t + k * NTH;
      xi[k] = (double)x[(size_t)i * EE + e];
      xj[k] = (double)x[(size_t)j * EE + e];
      xp[k] = (double)x[(size_t)p2 * EE + e];
      xn[k] = (double)x[(size_t)n2 * EE + e];
    }

    // ---- parent = tanh(xi*Wl + xj*Wr + b); fused 3-way partial sums ----
    double s0 = 0.0, s1 = 0.0, s2 = 0.0;
#pragma unroll
    for (int k = 0; k < EPT; ++k) {
      const double par = tanh(xi[k] * wl[k] + xj[k] * wr[k] + bv[k]);
      x[(size_t)j * EE + (t + k * NTH)] = (T)par;
      s0 += par * par;
      s1 += xp[k] * par;
      s2 += par * xn[k];
    }
    s1 = (p >= 0) ? s1 : 0.0;   // uniform select
    s2 = (nj >= 0) ? s2 : 0.0;
#pragma unroll
    for (int off = 32; off > 0; off >>= 1) {
      s0 += __shfl_down(s0, off, 64);
      s1 += __shfl_down(s1, off, 64);
      s2 += __shfl_down(s2, off, 64);
    }
    if (lane == 0) { r3[w][0] = s0; r3[w][1] = s1; r3[w][2] = s2; }
    __syncthreads();   // barrier B

    if (t == 0) {
      double t0 = 0.0, t1 = 0.0, t2 = 0.0;
#pragma unroll
      for (int k = 0; k < NW; ++k) { t0 += r3[k][0]; t1 += r3[k][1]; t2 += r3[k][2]; }
      const double nn = sqrt(t0);
      normL[j] = nn;
      cosL[i] = NEGINF;
      prevL[j] = p;
      if (p >= 0) {
        nextL[p] = j;
        cosL[p] = t1 / (fmax(normL[p], EPSD) * fmax(nn, EPSD));
      }
      cosL[j] = (nj >= 0) ? t2 / (fmax(nn, EPSD) * fmax(normL[nj], EPSD)) : NEGINF;
    }
    __syncthreads();   // barrier C
  }

  // Exactly one valid slot remains: the list head.
#pragma unroll
  for (int k = 0; k < EPT; ++k) {
    const int e = t + k * NTH;
    out[e] = (float)x[(size_t)head * EE + e];
  }
}

extern "C" void kernel_launch(void* const* d_in, const int* in_sizes, int n_in,
                              void* d_out, int out_size, void* d_ws, size_t ws_size,
                              hipStream_t stream) {
  const int* seqs = (const int*)d_in[0];
  const float* emb = (const float*)d_in[1];
  const float* Wl = (const float*)d_in[2];
  const float* Wr = (const float*)d_in[3];
  const float* Bb = (const float*)d_in[4];
  float* out = (float*)d_out;

  const size_t auxBytes = 2 * (size_t)SS * sizeof(double);
  const size_t xbytesD = (size_t)SS * EE * sizeof(double);

  if (ws_size >= xbytesD + auxBytes) {
    double* x = (double*)d_ws;
    double* norms = (double*)((char*)d_ws + xbytesD);
    double* num = norms + SS;
    hipLaunchKernelGGL((banyan_init<double>), dim3(SS), dim3(256), 0, stream, seqs, emb, x, norms);
    hipLaunchKernelGGL((banyan_dots<double>), dim3(SS - 1), dim3(256), 0, stream, x, num);
    hipLaunchKernelGGL((banyan_main<double>), dim3(1), dim3(NTH), 0, stream,
                       x, norms, num, Wl, Wr, Bb, out);
  } else {
    const size_t xbytesF = (size_t)SS * EE * sizeof(float);
    float* x = (float*)d_ws;
    double* norms = (double*)((char*)d_ws + xbytesF);
    double* num = norms + SS;
    hipLaunchKernelGGL((banyan_init<float>), dim3(SS), dim3(256), 0, stream, seqs, emb, x, norms);
    hipLaunchKernelGGL((banyan_dots<float>), dim3(SS - 1), dim3(256), 0, stream, x, num);
    hipLaunchKernelGGL((banyan_main<float>), dim3(1), dim3(NTH), 0, stream,
                       x, norms, num, Wl, Wr, Bb, out);
  }
}

// Round 3
// 5806.662 us; speedup vs baseline: 1.9936x; 1.1524x over previous
//
#include <hip/hip_runtime.h>
#include <math.h>

#define SS 2048
#define EE 1024
#define EPSD 1e-8
#define NTH 256          // 4 waves
#define EPT 4            // elements per thread (EE / NTH)
#define NW  4            // waves
#define NG  32           // cosine groups
#define GS  64           // group size (SS / NG)

__device__ __forceinline__ double wave_sum64(double v) {
#pragma unroll
  for (int off = 32; off > 0; off >>= 1) v += __shfl_down(v, off, 64);
  return v;
}

// Accurate-to-~1e-13 branchless f64 tanh for |z| <~ 1.2:
// t = tanh(z/2) via odd Taylor (exact rational coeffs) then tanh(z)=2t/(1+t^2).
__device__ __forceinline__ double tanh_fast(double z) {
  const double u = 0.5 * z;
  const double s = u * u;
  double p = -113927491862.0 / 2900518163668125.0;       // c23
  p = fma(p, s, 18888466084.0 / 194896477400625.0);      // c21
  p = fma(p, s, -443861162.0 / 1856156927625.0);         // c19
  p = fma(p, s, 6404582.0 / 10854718875.0);              // c17
  p = fma(p, s, -929569.0 / 638512875.0);                // c15
  p = fma(p, s, 21844.0 / 6081075.0);                    // c13
  p = fma(p, s, -1382.0 / 155925.0);                     // c11
  p = fma(p, s, 62.0 / 2835.0);                          // c9
  p = fma(p, s, -17.0 / 315.0);                          // c7
  p = fma(p, s, 2.0 / 15.0);                             // c5
  p = fma(p, s, -1.0 / 3.0);                             // c3
  const double t = fma(u * s, p, u);                     // tanh(z/2)
  const double den = fma(t, t, 1.0);
  return (2.0 * t) / den;
}

// Kernel A: gather x0 = emb[seqs], row norms in double.
template <typename T>
__global__ void banyan_init(const int* __restrict__ seqs, const float* __restrict__ emb,
                            T* __restrict__ x, double* __restrict__ norms) {
  __shared__ double sh[4];
  const int s = blockIdx.x;
  const int row = seqs[s];
  double acc = 0.0;
  for (int e = threadIdx.x; e < EE; e += 256) {
    const float v = emb[(size_t)row * EE + e];
    x[(size_t)s * EE + e] = (T)v;
    acc += (double)v * (double)v;
  }
  acc = wave_sum64(acc);
  const int lane = threadIdx.x & 63;
  const int w = threadIdx.x >> 6;
  if (lane == 0) sh[w] = acc;
  __syncthreads();
  if (threadIdx.x == 0) norms[s] = sqrt(sh[0] + sh[1] + sh[2] + sh[3]);
}

// Kernel B: initial adjacent-pair dots in double.
template <typename T>
__global__ void banyan_dots(const T* __restrict__ x, double* __restrict__ num) {
  __shared__ double sh[4];
  const int s = blockIdx.x;
  double acc = 0.0;
  for (int e = threadIdx.x; e < EE; e += 256) {
    acc += (double)x[(size_t)s * EE + e] * (double)x[(size_t)(s + 1) * EE + e];
  }
  acc = wave_sum64(acc);
  const int lane = threadIdx.x & 63;
  const int w = threadIdx.x >> 6;
  if (lane == 0) sh[w] = acc;
  __syncthreads();
  if (threadIdx.x == 0) num[s] = sh[0] + sh[1] + sh[2] + sh[3];
}

// Kernel C: persistent single-block merge loop with cached group maxima.
// Per step: wave0 32-entry argmax -> loads+tanh+3-sum reduce -> redundant
// finish + incremental group-max repair (waves 0-2) + scalar writes (wave 3).
template <typename T>
__global__ __launch_bounds__(NTH) void banyan_main(
    T* __restrict__ x, const double* __restrict__ norms_in, const double* __restrict__ num_in,
    const float* __restrict__ Wl, const float* __restrict__ Wr, const float* __restrict__ Bb,
    float* __restrict__ out) {
  __shared__ double cosL[SS];
  __shared__ double normL[SS];
  __shared__ int nextL[SS];
  __shared__ int prevL[SS];
  __shared__ double gVal[NG];
  __shared__ int gIdx[NG];
  __shared__ double r3[NW][3];
  __shared__ int sel[4];

  const int t = threadIdx.x;
  const int lane = t & 63;
  const int w = t >> 6;
  const double NEGINF = -__builtin_inf();

  for (int s = t; s < SS; s += NTH) {
    normL[s] = norms_in[s];
    nextL[s] = (s + 1 < SS) ? (s + 1) : -1;
    prevL[s] = s - 1;
  }
  __syncthreads();
  for (int s = t; s < SS; s += NTH) {
    cosL[s] = (s < SS - 1)
                  ? num_in[s] / (fmax(normL[s], EPSD) * fmax(normL[s + 1], EPSD))
                  : NEGINF;
  }
  __syncthreads();
  // Initial group maxima: each wave handles NG/NW groups.
  for (int m = 0; m < NG / NW; ++m) {
    const int g = w * (NG / NW) + m;
    double v = cosL[g * GS + lane];
    int ix = g * GS + lane;
#pragma unroll
    for (int off = 32; off > 0; off >>= 1) {
      const double ov = __shfl_down(v, off, 64);
      const int oi = __shfl_down(ix, off, 64);
      if (ov > v || (ov == v && oi < ix)) { v = ov; ix = oi; }
    }
    if (lane == 0) { gVal[g] = v; gIdx[g] = ix; }
  }
  __syncthreads();

  double wl[EPT], wr[EPT], bv[EPT];
#pragma unroll
  for (int k = 0; k < EPT; ++k) {
    const int e = t + k * NTH;
    wl[k] = (double)Wl[e];
    wr[k] = (double)Wr[e];
    bv[k] = (double)Bb[e];
  }
  int head = 0;

  for (int step = 0; step < SS - 1; ++step) {
    // ---- Phase 1: wave 0 argmax over 32 cached group maxima ----
    if (w == 0) {
      double v = (lane < NG) ? gVal[lane] : NEGINF;
      int ix = (lane < NG) ? gIdx[lane] : 0x7fffffff;
#pragma unroll
      for (int off = 32; off > 0; off >>= 1) {
        const double ov = __shfl_down(v, off, 64);
        const int oi = __shfl_down(ix, off, 64);
        if (ov > v || (ov == v && oi < ix)) { v = ov; ix = oi; }
      }
      if (lane == 0) {
        const int ii = ix;
        const int jj = nextL[ii];
        sel[0] = ii; sel[1] = jj; sel[2] = prevL[ii]; sel[3] = nextL[jj];
      }
    }
    __syncthreads();  // A
    const int i = __builtin_amdgcn_readfirstlane(sel[0]);
    const int j = __builtin_amdgcn_readfirstlane(sel[1]);
    const int p = __builtin_amdgcn_readfirstlane(sel[2]);
    const int nj = __builtin_amdgcn_readfirstlane(sel[3]);
    if (p < 0) head = j;
    const int p2 = (p >= 0) ? p : i;
    const int n2 = (nj >= 0) ? nj : i;

    // ---- Phase 2: row loads (one latency window), tanh, fused 3-sum ----
    double xi[EPT], xj[EPT], xp[EPT], xn[EPT];
#pragma unroll
    for (int k = 0; k < EPT; ++k) {
      const int e = t + k * NTH;
      xi[k] = (double)x[(size_t)i * EE + e];
      xj[k] = (double)x[(size_t)j * EE + e];
      xp[k] = (double)x[(size_t)p2 * EE + e];
      xn[k] = (double)x[(size_t)n2 * EE + e];
    }
    double s0 = 0.0, s1 = 0.0, s2 = 0.0;
#pragma unroll
    for (int k = 0; k < EPT; ++k) {
      const double par = tanh_fast(fma(xi[k], wl[k], fma(xj[k], wr[k], bv[k])));
      x[(size_t)j * EE + (t + k * NTH)] = (T)par;
      s0 += par * par;
      s1 += xp[k] * par;
      s2 += par * xn[k];
    }
    s1 = (p >= 0) ? s1 : 0.0;
    s2 = (nj >= 0) ? s2 : 0.0;
#pragma unroll
    for (int off = 32; off > 0; off >>= 1) {
      s0 += __shfl_down(s0, off, 64);
      s1 += __shfl_down(s1, off, 64);
      s2 += __shfl_down(s2, off, 64);
    }
    if (lane == 0) { r3[w][0] = s0; r3[w][1] = s1; r3[w][2] = s2; }
    __syncthreads();  // B

    // ---- Phase 3: redundant finish + group repair + scalar writes ----
    const double t0 = r3[0][0] + r3[1][0] + r3[2][0] + r3[3][0];
    const double t1 = r3[0][1] + r3[1][1] + r3[2][1] + r3[3][1];
    const double t2 = r3[0][2] + r3[1][2] + r3[2][2] + r3[3][2];
    const double nn = sqrt(t0);
    const double normP = normL[p2];
    const double normN = normL[n2];
    const double cosP = t1 / (fmax(normP, EPSD) * fmax(nn, EPSD));
    const double cosJnew = (nj >= 0) ? t2 / (fmax(nn, EPSD) * fmax(normN, EPSD)) : NEGINF;
    const int gi_ = i >> 6;
    const int gp_ = (p >= 0) ? (p >> 6) : gi_;
    const int gj_ = j >> 6;
    if (w < 3) {
      const int g = (w == 0) ? gi_ : (w == 1) ? gp_ : gj_;
      const int pos = g * GS + lane;
      double c = cosL[pos];            // racy read; changed slots masked below
      if (pos == i) c = NEGINF;
      if (p >= 0 && pos == p) c = cosP;
      if (pos == j) c = cosJnew;
      int ix = pos;
#pragma unroll
      for (int off = 32; off > 0; off >>= 1) {
        const double ov = __shfl_down(c, off, 64);
        const int oi = __shfl_down(ix, off, 64);
        if (ov > c || (ov == c && oi < ix)) { c = ov; ix = oi; }
      }
      if (lane == 0) { gVal[g] = c; gIdx[g] = ix; }  // dup groups write same value
    } else if (lane == 0) {  // wave 3: scalar list/cos updates
      cosL[i] = NEGINF;
      normL[j] = nn;
      prevL[j] = p;
      cosL[j] = cosJnew;
      if (p >= 0) { cosL[p] = cosP; nextL[p] = j; }
    }
    __syncthreads();  // C
  }

#pragma unroll
  for (int k = 0; k < EPT; ++k) {
    const int e = t + k * NTH;
    out[e] = (float)x[(size_t)head * EE + e];
  }
}

extern "C" void kernel_launch(void* const* d_in, const int* in_sizes, int n_in,
                              void* d_out, int out_size, void* d_ws, size_t ws_size,
                              hipStream_t stream) {
  const int* seqs = (const int*)d_in[0];
  const float* emb = (const float*)d_in[1];
  const float* Wl = (const float*)d_in[2];
  const float* Wr = (const float*)d_in[3];
  const float* Bb = (const float*)d_in[4];
  float* out = (float*)d_out;

  const size_t auxBytes = 2 * (size_t)SS * sizeof(double);
  const size_t xbytesD = (size_t)SS * EE * sizeof(double);

  if (ws_size >= xbytesD + auxBytes) {
    double* x = (double*)d_ws;
    double* norms = (double*)((char*)d_ws + xbytesD);
    double* num = norms + SS;
    hipLaunchKernelGGL((banyan_init<double>), dim3(SS), dim3(256), 0, stream, seqs, emb, x, norms);
    hipLaunchKernelGGL((banyan_dots<double>), dim3(SS - 1), dim3(256), 0, stream, x, num);
    hipLaunchKernelGGL((banyan_main<double>), dim3(1), dim3(NTH), 0, stream,
                       x, norms, num, Wl, Wr, Bb, out);
  } else {
    const size_t xbytesF = (size_t)SS * EE * sizeof(float);
    float* x = (float*)d_ws;
    double* norms = (double*)((char*)d_ws + xbytesF);
    double* num = norms + SS;
    hipLaunchKernelGGL((banyan_init<float>), dim3(SS), dim3(256), 0, stream, seqs, emb, x, norms);
    hipLaunchKernelGGL((banyan_dots<float>), dim3(SS - 1), dim3(256), 0, stream, x, num);
    hipLaunchKernelGGL((banyan_main<float>), dim3(1), dim3(NTH), 0, stream,
                       x, norms, num, Wl, Wr, Bb, out);
  }
}

// Round 4
// 4817.585 us; speedup vs baseline: 2.4029x; 1.2053x over previous
//
#include <hip/hip_runtime.h>
#include <math.h>

#define SS 2048
#define EE 1024
#define EPSD 1e-8
#define NTH 256          // 4 waves, 1 per SIMD
#define NW  4
#define NG  32           // cosine groups
#define GS  64           // group size

template <typename T> struct VecT;
template <> struct VecT<double> { using t2 = double __attribute__((ext_vector_type(2))); };
template <> struct VecT<float>  { using t2 = float  __attribute__((ext_vector_type(2))); };

__device__ __forceinline__ double wave_sum64(double v) {
#pragma unroll
  for (int off = 32; off > 0; off >>= 1) v += __shfl_down(v, off, 64);
  return v;
}

// ~1e-13-accurate branchless f64 tanh for |z| <~ 1.2.
__device__ __forceinline__ double tanh_fast(double z) {
  const double u = 0.5 * z;
  const double s = u * u;
  double p = -113927491862.0 / 2900518163668125.0;
  p = fma(p, s, 18888466084.0 / 194896477400625.0);
  p = fma(p, s, -443861162.0 / 1856156927625.0);
  p = fma(p, s, 6404582.0 / 10854718875.0);
  p = fma(p, s, -929569.0 / 638512875.0);
  p = fma(p, s, 21844.0 / 6081075.0);
  p = fma(p, s, -1382.0 / 155925.0);
  p = fma(p, s, 62.0 / 2835.0);
  p = fma(p, s, -17.0 / 315.0);
  p = fma(p, s, 2.0 / 15.0);
  p = fma(p, s, -1.0 / 3.0);
  const double t = fma(u * s, p, u);          // tanh(z/2)
  return (2.0 * t) / fma(t, t, 1.0);
}

template <typename T>
__global__ void banyan_init(const int* __restrict__ seqs, const float* __restrict__ emb,
                            T* __restrict__ x, double* __restrict__ norms) {
  __shared__ double sh[4];
  const int s = blockIdx.x;
  const int row = seqs[s];
  double acc = 0.0;
  for (int e = threadIdx.x; e < EE; e += 256) {
    const float v = emb[(size_t)row * EE + e];
    x[(size_t)s * EE + e] = (T)v;
    acc += (double)v * (double)v;
  }
  acc = wave_sum64(acc);
  const int lane = threadIdx.x & 63;
  const int w = threadIdx.x >> 6;
  if (lane == 0) sh[w] = acc;
  __syncthreads();
  if (threadIdx.x == 0) norms[s] = sqrt(sh[0] + sh[1] + sh[2] + sh[3]);
}

template <typename T>
__global__ void banyan_dots(const T* __restrict__ x, double* __restrict__ num) {
  __shared__ double sh[4];
  const int s = blockIdx.x;
  double acc = 0.0;
  for (int e = threadIdx.x; e < EE; e += 256) {
    acc += (double)x[(size_t)s * EE + e] * (double)x[(size_t)(s + 1) * EE + e];
  }
  acc = wave_sum64(acc);
  const int lane = threadIdx.x & 63;
  const int w = threadIdx.x >> 6;
  if (lane == 0) sh[w] = acc;
  __syncthreads();
  if (threadIdx.x == 0) num[s] = sh[0] + sh[1] + sh[2] + sh[3];
}

// Persistent single-block merge loop. 2 barriers/step:
//   argmax (all-wave redundant, no barrier) -> loads+tanh+reduce [B]
//   finish + group repair + scalar writes [C]
template <typename T>
__global__ __launch_bounds__(NTH, 1) void banyan_main(
    T* __restrict__ x, const double* __restrict__ norms_in, const double* __restrict__ num_in,
    const float* __restrict__ Wl, const float* __restrict__ Wr, const float* __restrict__ Bb,
    float* __restrict__ out) {
  __shared__ double cosL[SS];
  __shared__ double normL[SS];
  __shared__ unsigned listL[SS];   // next in low16, prev in high16 (0xFFFF = -1)
  __shared__ double gVal[NG];
  __shared__ int gIdx[NG];
  __shared__ double r3[NW][3];

  using T2 = typename VecT<T>::t2;
  const int t = threadIdx.x;
  const int lane = t & 63;
  const int w = t >> 6;
  const double NEGINF = -__builtin_inf();

  for (int s = t; s < SS; s += NTH) {
    normL[s] = norms_in[s];
    const int nx = (s + 1 < SS) ? (s + 1) : -1;
    const int pv = s - 1;
    listL[s] = ((unsigned)nx & 0xFFFFu) | (((unsigned)pv & 0xFFFFu) << 16);
  }
  __syncthreads();
  for (int s = t; s < SS; s += NTH) {
    cosL[s] = (s < SS - 1)
                  ? num_in[s] / (fmax(normL[s], EPSD) * fmax(normL[s + 1], EPSD))
                  : NEGINF;
  }
  __syncthreads();
  for (int m = 0; m < NG / NW; ++m) {
    const int g = w * (NG / NW) + m;
    double v = cosL[g * GS + lane];
    int ix = g * GS + lane;
#pragma unroll
    for (int off = 32; off > 0; off >>= 1) {
      const double ov = __shfl_down(v, off, 64);
      const int oi = __shfl_down(ix, off, 64);
      if (ov > v || (ov == v && oi < ix)) { v = ov; ix = oi; }
    }
    if (lane == 0) { gVal[g] = v; gIdx[g] = ix; }
  }
  __syncthreads();

  // Thread t owns elements {2t, 2t+1, 512+2t, 512+2t+1} (coalesced 16B chunks).
  const int e0 = 2 * t;
  double wl0 = (double)Wl[e0],       wl1 = (double)Wl[e0 + 1];
  double wl2 = (double)Wl[e0 + 512], wl3 = (double)Wl[e0 + 513];
  double wr0 = (double)Wr[e0],       wr1 = (double)Wr[e0 + 1];
  double wr2 = (double)Wr[e0 + 512], wr3 = (double)Wr[e0 + 513];
  double bv0 = (double)Bb[e0],       bv1 = (double)Bb[e0 + 1];
  double bv2 = (double)Bb[e0 + 512], bv3 = (double)Bb[e0 + 513];
  int head = 0;

  for (int step = 0; step < SS - 1; ++step) {
    // ---- argmax over 32 cached group maxima: all waves, redundant ----
    double v = (lane < NG) ? gVal[lane] : NEGINF;
    int ix = (lane < NG) ? gIdx[lane] : 0x7fffffff;
#pragma unroll
    for (int m = 16; m > 0; m >>= 1) {
      const double ov = __shfl_xor(v, m, 64);
      const int oi = __shfl_xor(ix, m, 64);
      if (ov > v || (ov == v && oi < ix)) { v = ov; ix = oi; }
    }
    const int i = __shfl(ix, 0, 64);                 // broadcast from lane 0
    const unsigned pki = listL[i];                   // broadcast LDS read
    const int j = (int)(short)(pki & 0xFFFFu);
    const int p = (int)(short)(pki >> 16);
    const unsigned pkj = listL[j];
    const int nj = (int)(short)(pkj & 0xFFFFu);
    if (p < 0) head = j;
    const int p2 = (p >= 0) ? p : i;
    const int n2 = (nj >= 0) ? nj : i;

    // ---- phase 2: all global loads in ONE latency window ----
    const T2 xiA = *(const T2*)&x[(size_t)i * EE + e0];
    const T2 xiB = *(const T2*)&x[(size_t)i * EE + e0 + 512];
    const T2 xjA = *(const T2*)&x[(size_t)j * EE + e0];
    const T2 xjB = *(const T2*)&x[(size_t)j * EE + e0 + 512];
    const T2 xpA = *(const T2*)&x[(size_t)p2 * EE + e0];
    const T2 xpB = *(const T2*)&x[(size_t)p2 * EE + e0 + 512];
    const T2 xnA = *(const T2*)&x[(size_t)n2 * EE + e0];
    const T2 xnB = *(const T2*)&x[(size_t)n2 * EE + e0 + 512];
    // overlap LDS preloads with the global-load window
    const double normP = normL[p2];
    const double normN = normL[n2];
    const int gi_ = i >> 6;
    const int gp_ = (p >= 0) ? (p >> 6) : gi_;
    const int gj_ = j >> 6;
    const int grp = (w == 0) ? gi_ : (w == 1) ? gp_ : gj_;
    const int pos = grp * GS + lane;
    const double cPre = cosL[pos];   // stable except 3 slots, masked in phase 3

    const double p0 = tanh_fast(fma((double)xiA.x, wl0, fma((double)xjA.x, wr0, bv0)));
    const double p1 = tanh_fast(fma((double)xiA.y, wl1, fma((double)xjA.y, wr1, bv1)));
    const double p2v = tanh_fast(fma((double)xiB.x, wl2, fma((double)xjB.x, wr2, bv2)));
    const double p3 = tanh_fast(fma((double)xiB.y, wl3, fma((double)xjB.y, wr3, bv3)));
    T2 st0; st0.x = (T)p0; st0.y = (T)p1;
    T2 st1; st1.x = (T)p2v; st1.y = (T)p3;
    *(T2*)&x[(size_t)j * EE + e0] = st0;
    *(T2*)&x[(size_t)j * EE + e0 + 512] = st1;

    double s0 = fma(p0, p0, fma(p1, p1, fma(p2v, p2v, p3 * p3)));
    double s1 = fma((double)xpA.x, p0, fma((double)xpA.y, p1,
                fma((double)xpB.x, p2v, (double)xpB.y * p3)));
    double s2 = fma(p0, (double)xnA.x, fma(p1, (double)xnA.y,
                fma(p2v, (double)xnB.x, p3 * (double)xnB.y)));
    s1 = (p >= 0) ? s1 : 0.0;
    s2 = (nj >= 0) ? s2 : 0.0;
#pragma unroll
    for (int off = 32; off > 0; off >>= 1) {
      s0 += __shfl_down(s0, off, 64);
      s1 += __shfl_down(s1, off, 64);
      s2 += __shfl_down(s2, off, 64);
    }
    if (lane == 0) { r3[w][0] = s0; r3[w][1] = s1; r3[w][2] = s2; }
    __syncthreads();  // B

    // ---- phase 3: redundant finish + group repair + scalar writes ----
    const double t0 = (r3[0][0] + r3[1][0]) + (r3[2][0] + r3[3][0]);
    const double t1 = (r3[0][1] + r3[1][1]) + (r3[2][1] + r3[3][1]);
    const double t2 = (r3[0][2] + r3[1][2]) + (r3[2][2] + r3[3][2]);
    const double nn = sqrt(t0);
    const double cosP = t1 / (fmax(normP, EPSD) * fmax(nn, EPSD));
    const double cosJnew = (nj >= 0) ? t2 / (fmax(nn, EPSD) * fmax(normN, EPSD)) : NEGINF;
    if (w < 3) {
      double c = cPre;
      if (pos == i) c = NEGINF;
      if (p >= 0 && pos == p) c = cosP;
      if (pos == j) c = cosJnew;
      int gx = pos;
#pragma unroll
      for (int off = 32; off > 0; off >>= 1) {
        const double ov = __shfl_down(c, off, 64);
        const int oi = __shfl_down(gx, off, 64);
        if (ov > c || (ov == c && oi < gx)) { c = ov; gx = oi; }
      }
      if (lane == 0) { gVal[grp] = c; gIdx[grp] = gx; }
    } else if (lane == 0) {  // wave 3: scalar LDS state updates
      cosL[i] = NEGINF;
      cosL[j] = cosJnew;
      normL[j] = nn;
      listL[j] = ((unsigned)nj & 0xFFFFu) | (((unsigned)p & 0xFFFFu) << 16);
      if (p >= 0) {
        cosL[p] = cosP;
        listL[p] = (listL[p] & 0xFFFF0000u) | ((unsigned)j & 0xFFFFu);
      }
    }
    __syncthreads();  // C
  }

  {
    const T2 ha = *(const T2*)&x[(size_t)head * EE + e0];
    const T2 hb = *(const T2*)&x[(size_t)head * EE + e0 + 512];
    out[e0] = (float)ha.x;
    out[e0 + 1] = (float)ha.y;
    out[e0 + 512] = (float)hb.x;
    out[e0 + 513] = (float)hb.y;
  }
}

extern "C" void kernel_launch(void* const* d_in, const int* in_sizes, int n_in,
                              void* d_out, int out_size, void* d_ws, size_t ws_size,
                              hipStream_t stream) {
  const int* seqs = (const int*)d_in[0];
  const float* emb = (const float*)d_in[1];
  const float* Wl = (const float*)d_in[2];
  const float* Wr = (const float*)d_in[3];
  const float* Bb = (const float*)d_in[4];
  float* out = (float*)d_out;

  const size_t auxBytes = 2 * (size_t)SS * sizeof(double);
  const size_t xbytesD = (size_t)SS * EE * sizeof(double);

  if (ws_size >= xbytesD + auxBytes) {
    double* x = (double*)d_ws;
    double* norms = (double*)((char*)d_ws + xbytesD);
    double* num = norms + SS;
    hipLaunchKernelGGL((banyan_init<double>), dim3(SS), dim3(256), 0, stream, seqs, emb, x, norms);
    hipLaunchKernelGGL((banyan_dots<double>), dim3(SS - 1), dim3(256), 0, stream, x, num);
    hipLaunchKernelGGL((banyan_main<double>), dim3(1), dim3(NTH), 0, stream,
                       x, norms, num, Wl, Wr, Bb, out);
  } else {
    const size_t xbytesF = (size_t)SS * EE * sizeof(float);
    float* x = (float*)d_ws;
    double* norms = (double*)((char*)d_ws + xbytesF);
    double* num = norms + SS;
    hipLaunchKernelGGL((banyan_init<float>), dim3(SS), dim3(256), 0, stream, seqs, emb, x, norms);
    hipLaunchKernelGGL((banyan_dots<float>), dim3(SS - 1), dim3(256), 0, stream, x, num);
    hipLaunchKernelGGL((banyan_main<float>), dim3(1), dim3(NTH), 0, stream,
                       x, norms, num, Wl, Wr, Bb, out);
  }
}

// Round 5
// 3869.926 us; speedup vs baseline: 2.9913x; 1.2449x over previous
//
#include <hip/hip_runtime.h>
#include <math.h>

#define SS 2048
#define EE 1024
#define EPSD 1e-8
#define NTH 256          // 4 waves, 1 per SIMD
#define NW  4
#define NG  32           // cosine groups
#define GS  64           // group size

#define DPP_XOR1 0xB1    // quad_perm [1,0,3,2]
#define DPP_XOR2 0x4E    // quad_perm [2,3,0,1]
#define DPP_HMIR 0x141   // row_half_mirror (8-lane mirror)
#define DPP_MIR  0x140   // row_mirror (16-lane mirror)

template <typename T> struct VecT;
template <> struct VecT<double> { using t2 = double __attribute__((ext_vector_type(2))); };
template <> struct VecT<float>  { using t2 = float  __attribute__((ext_vector_type(2))); };

template <int CTRL>
__device__ __forceinline__ double mov_dpp_f64(double v) {
  union { double d; unsigned long long u; } a;
  a.d = v;
  const int lo = (int)(unsigned)(a.u & 0xFFFFFFFFull);
  const int hi = (int)(unsigned)(a.u >> 32);
  const int nlo = __builtin_amdgcn_mov_dpp(lo, CTRL, 0xF, 0xF, true);
  const int nhi = __builtin_amdgcn_mov_dpp(hi, CTRL, 0xF, 0xF, true);
  union { unsigned long long u; double d; } r;
  r.u = ((unsigned long long)(unsigned)nhi << 32) | (unsigned long long)(unsigned)nlo;
  return r.d;
}

template <int CTRL>
__device__ __forceinline__ double dpp_add(double v) { return v + mov_dpp_f64<CTRL>(v); }

template <int CTRL>
__device__ __forceinline__ void amax_dpp(double& v, int& ix) {
  const double ov = mov_dpp_f64<CTRL>(v);
  const int oi = __builtin_amdgcn_mov_dpp(ix, CTRL, 0xF, 0xF, true);
  if (ov > v || (ov == v && oi < ix)) { v = ov; ix = oi; }
}

__device__ __forceinline__ void amax_xor(double& v, int& ix, int m) {
  const double ov = __shfl_xor(v, m, 64);
  const int oi = __shfl_xor(ix, m, 64);
  if (ov > v || (ov == v && oi < ix)) { v = ov; ix = oi; }
}

__device__ __forceinline__ double wave_sum64(double v) {
#pragma unroll
  for (int off = 32; off > 0; off >>= 1) v += __shfl_down(v, off, 64);
  return v;
}

// ~1e-13-accurate branchless f64 tanh for |z| <~ 1.2.
__device__ __forceinline__ double tanh_fast(double z) {
  const double u = 0.5 * z;
  const double s = u * u;
  double p = -113927491862.0 / 2900518163668125.0;
  p = fma(p, s, 18888466084.0 / 194896477400625.0);
  p = fma(p, s, -443861162.0 / 1856156927625.0);
  p = fma(p, s, 6404582.0 / 10854718875.0);
  p = fma(p, s, -929569.0 / 638512875.0);
  p = fma(p, s, 21844.0 / 6081075.0);
  p = fma(p, s, -1382.0 / 155925.0);
  p = fma(p, s, 62.0 / 2835.0);
  p = fma(p, s, -17.0 / 315.0);
  p = fma(p, s, 2.0 / 15.0);
  p = fma(p, s, -1.0 / 3.0);
  const double t = fma(u * s, p, u);          // tanh(z/2)
  return (2.0 * t) / fma(t, t, 1.0);
}

template <typename T>
__global__ void banyan_init(const int* __restrict__ seqs, const float* __restrict__ emb,
                            T* __restrict__ x, double* __restrict__ norms) {
  __shared__ double sh[4];
  const int s = blockIdx.x;
  const int row = seqs[s];
  double acc = 0.0;
  for (int e = threadIdx.x; e < EE; e += 256) {
    const float v = emb[(size_t)row * EE + e];
    x[(size_t)s * EE + e] = (T)v;
    acc += (double)v * (double)v;
  }
  acc = wave_sum64(acc);
  const int lane = threadIdx.x & 63;
  const int w = threadIdx.x >> 6;
  if (lane == 0) sh[w] = acc;
  __syncthreads();
  if (threadIdx.x == 0) norms[s] = sqrt(sh[0] + sh[1] + sh[2] + sh[3]);
}

template <typename T>
__global__ void banyan_dots(const T* __restrict__ x, double* __restrict__ num) {
  __shared__ double sh[4];
  const int s = blockIdx.x;
  double acc = 0.0;
  for (int e = threadIdx.x; e < EE; e += 256) {
    acc += (double)x[(size_t)s * EE + e] * (double)x[(size_t)(s + 1) * EE + e];
  }
  acc = wave_sum64(acc);
  const int lane = threadIdx.x & 63;
  const int w = threadIdx.x >> 6;
  if (lane == 0) sh[w] = acc;
  __syncthreads();
  if (threadIdx.x == 0) num[s] = sh[0] + sh[1] + sh[2] + sh[3];
}

// Persistent single-block merge loop. 2 barriers/step; DPP cross-lane.
template <typename T>
__global__ __launch_bounds__(NTH, 1) void banyan_main(
    T* __restrict__ x, const double* __restrict__ norms_in, const double* __restrict__ num_in,
    const float* __restrict__ Wl, const float* __restrict__ Wr, const float* __restrict__ Bb,
    float* __restrict__ out) {
  __shared__ double cosL[SS];
  __shared__ double normL[SS];
  __shared__ unsigned listL[SS];   // next in low16, prev in high16 (0xFFFF = -1)
  __shared__ int next2L[SS];       // next[next[s]] (-1 = none)
  __shared__ double gVal[NG];
  __shared__ int gIdx[NG];
  __shared__ double r3[3][NW * 2]; // [sum][wave*2 + half]

  using T2 = typename VecT<T>::t2;
  const int t = threadIdx.x;
  const int lane = t & 63;
  const int w = t >> 6;
  const double NEGINF = -__builtin_inf();

  for (int s = t; s < SS; s += NTH) {
    normL[s] = norms_in[s];
    const int nx = (s + 1 < SS) ? (s + 1) : -1;
    const int pv = s - 1;
    listL[s] = ((unsigned)nx & 0xFFFFu) | (((unsigned)pv & 0xFFFFu) << 16);
    next2L[s] = (s + 2 < SS) ? (s + 2) : -1;
  }
  __syncthreads();
  for (int s = t; s < SS; s += NTH) {
    cosL[s] = (s < SS - 1)
                  ? num_in[s] / (fmax(normL[s], EPSD) * fmax(normL[s + 1], EPSD))
                  : NEGINF;
  }
  __syncthreads();
  for (int m = 0; m < NG / NW; ++m) {
    const int g = w * (NG / NW) + m;
    double v = cosL[g * GS + lane];
    int ix = g * GS + lane;
#pragma unroll
    for (int off = 32; off > 0; off >>= 1) {
      const double ov = __shfl_down(v, off, 64);
      const int oi = __shfl_down(ix, off, 64);
      if (ov > v || (ov == v && oi < ix)) { v = ov; ix = oi; }
    }
    if (lane == 0) { gVal[g] = v; gIdx[g] = ix; }
  }
  __syncthreads();

  // Thread t owns elements {2t, 2t+1, 512+2t, 512+2t+1}.
  const int e0 = 2 * t;
  const double wl0 = (double)Wl[e0],       wl1 = (double)Wl[e0 + 1];
  const double wl2 = (double)Wl[e0 + 512], wl3 = (double)Wl[e0 + 513];
  const double wr0 = (double)Wr[e0],       wr1 = (double)Wr[e0 + 1];
  const double wr2 = (double)Wr[e0 + 512], wr3 = (double)Wr[e0 + 513];
  const double bv0 = (double)Bb[e0],       bv1 = (double)Bb[e0 + 1];
  const double bv2 = (double)Bb[e0 + 512], bv3 = (double)Bb[e0 + 513];
  int head = 0;

  for (int step = 0; step < SS - 1; ++step) {
    // ---- phase 1: argmax over 32 group maxima (both halves duplicate) ----
    double v = gVal[lane & 31];
    int ix = gIdx[lane & 31];
    amax_dpp<DPP_XOR1>(v, ix);
    amax_dpp<DPP_XOR2>(v, ix);
    amax_dpp<DPP_HMIR>(v, ix);
    amax_dpp<DPP_MIR>(v, ix);
    amax_xor(v, ix, 16);             // each 32-half now has argmax of all 32
    const int i = __builtin_amdgcn_readfirstlane(ix);
    const unsigned pki = listL[i];   // broadcast LDS reads, issued together
    const int nj_raw = next2L[i];
    const int j = __builtin_amdgcn_readfirstlane((int)(short)(pki & 0xFFFFu));
    const int p = __builtin_amdgcn_readfirstlane((int)(short)(pki >> 16));
    const int nj = __builtin_amdgcn_readfirstlane(nj_raw);
    if (p < 0) head = j;
    const int p2 = (p >= 0) ? p : i;
    const int n2 = (nj >= 0) ? nj : i;

    // ---- phase 2: global loads in one window, tanh, DPP 3-sum ----
    const T2 xiA = *(const T2*)&x[(size_t)i * EE + e0];
    const T2 xiB = *(const T2*)&x[(size_t)i * EE + e0 + 512];
    const T2 xjA = *(const T2*)&x[(size_t)j * EE + e0];
    const T2 xjB = *(const T2*)&x[(size_t)j * EE + e0 + 512];
    const T2 xpA = *(const T2*)&x[(size_t)p2 * EE + e0];
    const T2 xpB = *(const T2*)&x[(size_t)p2 * EE + e0 + 512];
    const T2 xnA = *(const T2*)&x[(size_t)n2 * EE + e0];
    const T2 xnB = *(const T2*)&x[(size_t)n2 * EE + e0 + 512];
    const double normP = normL[p2];
    const double normN = normL[n2];
    const int gi_ = i >> 6;
    const int gp_ = (p >= 0) ? (p >> 6) : gi_;
    const int gj_ = j >> 6;
    const int grp = (w == 0) ? gi_ : (w == 1) ? gp_ : gj_;
    const int pos = grp * GS + lane;
    const double cPre = cosL[pos];   // stable except 3 slots, masked in phase 3

    const double p0 = tanh_fast(fma((double)xiA.x, wl0, fma((double)xjA.x, wr0, bv0)));
    const double p1 = tanh_fast(fma((double)xiA.y, wl1, fma((double)xjA.y, wr1, bv1)));
    const double p2v = tanh_fast(fma((double)xiB.x, wl2, fma((double)xjB.x, wr2, bv2)));
    const double p3 = tanh_fast(fma((double)xiB.y, wl3, fma((double)xjB.y, wr3, bv3)));
    T2 st0; st0.x = (T)p0; st0.y = (T)p1;
    T2 st1; st1.x = (T)p2v; st1.y = (T)p3;
    *(T2*)&x[(size_t)j * EE + e0] = st0;
    *(T2*)&x[(size_t)j * EE + e0 + 512] = st1;

    double s0 = fma(p0, p0, fma(p1, p1, fma(p2v, p2v, p3 * p3)));
    double s1 = fma((double)xpA.x, p0, fma((double)xpA.y, p1,
                fma((double)xpB.x, p2v, (double)xpB.y * p3)));
    double s2 = fma(p0, (double)xnA.x, fma(p1, (double)xnA.y,
                fma(p2v, (double)xnB.x, p3 * (double)xnB.y)));
    s1 = (p >= 0) ? s1 : 0.0;
    s2 = (nj >= 0) ? s2 : 0.0;
    s0 = dpp_add<DPP_XOR1>(s0); s1 = dpp_add<DPP_XOR1>(s1); s2 = dpp_add<DPP_XOR1>(s2);
    s0 = dpp_add<DPP_XOR2>(s0); s1 = dpp_add<DPP_XOR2>(s1); s2 = dpp_add<DPP_XOR2>(s2);
    s0 = dpp_add<DPP_HMIR>(s0); s1 = dpp_add<DPP_HMIR>(s1); s2 = dpp_add<DPP_HMIR>(s2);
    s0 = dpp_add<DPP_MIR>(s0);  s1 = dpp_add<DPP_MIR>(s1);  s2 = dpp_add<DPP_MIR>(s2);
    s0 += __shfl_xor(s0, 16, 64);
    s1 += __shfl_xor(s1, 16, 64);
    s2 += __shfl_xor(s2, 16, 64);
    if ((lane & 31) == 0) {          // lanes 0 and 32: 32-half partials
      const int slot = w * 2 + (lane >> 5);
      r3[0][slot] = s0; r3[1][slot] = s1; r3[2][slot] = s2;
    }
    __syncthreads();  // B

    // ---- phase 3: redundant finish + group repair + scalar writes ----
    double t0 = 0.0, t1 = 0.0, t2 = 0.0;
#pragma unroll
    for (int m = 0; m < NW * 2; ++m) { t0 += r3[0][m]; t1 += r3[1][m]; t2 += r3[2][m]; }
    const double nn = sqrt(t0);
    const double cosP = t1 / (fmax(normP, EPSD) * fmax(nn, EPSD));
    const double cosJnew = (nj >= 0) ? t2 / (fmax(nn, EPSD) * fmax(normN, EPSD)) : NEGINF;
    if (w < 3) {
      double c = cPre;
      if (pos == i) c = NEGINF;
      if (p >= 0 && pos == p) c = cosP;
      if (pos == j) c = cosJnew;
      int gx = pos;
      amax_dpp<DPP_XOR1>(c, gx);
      amax_dpp<DPP_XOR2>(c, gx);
      amax_dpp<DPP_HMIR>(c, gx);
      amax_dpp<DPP_MIR>(c, gx);
      amax_xor(c, gx, 16);
      amax_xor(c, gx, 32);
      if (lane == 0) { gVal[grp] = c; gIdx[grp] = gx; }  // dup groups: same value
    } else if (lane == 0) {  // wave 3: scalar LDS state updates
      cosL[i] = NEGINF;
      cosL[j] = cosJnew;
      normL[j] = nn;
      listL[j] = ((unsigned)nj & 0xFFFFu) | (((unsigned)p & 0xFFFFu) << 16);
      if (p >= 0) {
        cosL[p] = cosP;
        const unsigned lp = listL[p];
        listL[p] = (lp & 0xFFFF0000u) | ((unsigned)j & 0xFFFFu);
        next2L[p] = nj;
        const int pp = (int)(short)(lp >> 16);
        if (pp >= 0) next2L[pp] = j;
      }
    }
    __syncthreads();  // C
  }

  {
    const T2 ha = *(const T2*)&x[(size_t)head * EE + e0];
    const T2 hb = *(const T2*)&x[(size_t)head * EE + e0 + 512];
    out[e0] = (float)ha.x;
    out[e0 + 1] = (float)ha.y;
    out[e0 + 512] = (float)hb.x;
    out[e0 + 513] = (float)hb.y;
  }
}

extern "C" void kernel_launch(void* const* d_in, const int* in_sizes, int n_in,
                              void* d_out, int out_size, void* d_ws, size_t ws_size,
                              hipStream_t stream) {
  const int* seqs = (const int*)d_in[0];
  const float* emb = (const float*)d_in[1];
  const float* Wl = (const float*)d_in[2];
  const float* Wr = (const float*)d_in[3];
  const float* Bb = (const float*)d_in[4];
  float* out = (float*)d_out;

  const size_t auxBytes = 2 * (size_t)SS * sizeof(double);
  const size_t xbytesD = (size_t)SS * EE * sizeof(double);

  if (ws_size >= xbytesD + auxBytes) {
    double* x = (double*)d_ws;
    double* norms = (double*)((char*)d_ws + xbytesD);
    double* num = norms + SS;
    hipLaunchKernelGGL((banyan_init<double>), dim3(SS), dim3(256), 0, stream, seqs, emb, x, norms);
    hipLaunchKernelGGL((banyan_dots<double>), dim3(SS - 1), dim3(256), 0, stream, x, num);
    hipLaunchKernelGGL((banyan_main<double>), dim3(1), dim3(NTH), 0, stream,
                       x, norms, num, Wl, Wr, Bb, out);
  } else {
    const size_t xbytesF = (size_t)SS * EE * sizeof(float);
    float* x = (float*)d_ws;
    double* norms = (double*)((char*)d_ws + xbytesF);
    double* num = norms + SS;
    hipLaunchKernelGGL((banyan_init<float>), dim3(SS), dim3(256), 0, stream, seqs, emb, x, norms);
    hipLaunchKernelGGL((banyan_dots<float>), dim3(SS - 1), dim3(256), 0, stream, x, num);
    hipLaunchKernelGGL((banyan_main<float>), dim3(1), dim3(NTH), 0, stream,
                       x, norms, num, Wl, Wr, Bb, out);
  }
}